// Round 2
// baseline (1069.973 us; speedup 1.0000x reference)
//
#include <hip/hip_runtime.h>
#include <hip/hip_bf16.h>

typedef __bf16 bf16_t;
typedef __bf16 bf16x4 __attribute__((ext_vector_type(4)));
typedef __bf16 bf16x8 __attribute__((ext_vector_type(8)));
typedef float f32x4 __attribute__((ext_vector_type(4)));

#define B_ 32
#define N_ 16384
#define C_ 256
#define D_ 64
#define ROWS_TOTAL (B_ * N_)  // 524288
#define MAXCH 128             // max partial chunks per b (proj path)

__device__ inline float wave_sum64(float v) {
#pragma unroll
  for (int o = 1; o < 64; o <<= 1) v += __shfl_xor(v, o);
  return v;
}

__device__ inline float sigmoidf_(float x) { return 1.0f / (1.0f + __expf(-x)); }
__device__ inline float tanhf_(float x) { return 1.0f - 2.0f / (__expf(2.0f * x) + 1.0f); }

// ---------------------------------------------------------------------------
// prep (+ fused qk): blocks 0..279: Wb = [Wk|Wv] in MFMA B-frag layout,
// transpose GRU weights, g = slots. Blocks 280..335 (224 waves): iteration-0
// q = LN(slots[b,m]) @ Wq/bWq (q depends only on slots, so no ordering dep).
// grid 336 x 256.
// ---------------------------------------------------------------------------
__global__ __launch_bounds__(256) void prep_kernel(
    const float* __restrict__ Wk, const float* __restrict__ Wv,
    const float* __restrict__ Wih, const float* __restrict__ Whh,
    const float* __restrict__ slots, const float* __restrict__ qg,
    const float* __restrict__ qb, const float* __restrict__ Wq,
    const float* __restrict__ bqg, const float* __restrict__ bqb,
    const float* __restrict__ bWq, bf16_t* __restrict__ Wb,
    float* __restrict__ WihT, float* __restrict__ WhhT, float* __restrict__ g,
    float* __restrict__ q) {
  __shared__ float sx[256];
  if (blockIdx.x < 280) {
    int i = blockIdx.x * 256 + threadIdx.x;
    if (i < 32768) {
      int j = i & 7, l = (i >> 3) & 63, t = (i >> 9) & 7, kb = i >> 12;
      int k = kb * 32 + (l >> 4) * 8 + j;
      int n = t * 16 + (l & 15);
      float v = (n < 64) ? Wk[k * 64 + n] : Wv[k * 64 + (n - 64)];
      Wb[i] = (bf16_t)v;
    } else if (i < 45056) {
      int idx = i - 32768;
      int c = idx / 192, j = idx % 192;
      WihT[idx] = Wih[j * 64 + c];
    } else if (i < 57344) {
      int idx = i - 45056;
      int c = idx / 192, j = idx % 192;
      WhhT[idx] = Whh[j * 64 + c];
    } else if (i < 71680) {
      int idx = i - 57344;
      g[idx] = slots[idx];
    }
  } else {
    int w = threadIdx.x >> 6, lane = threadIdx.x & 63;
    int bid = (blockIdx.x - 280) * 4 + w;  // 0..223 = b*7+m
    int m = bid % 7;
    const float* lng = (m < 6) ? qg : bqg;
    const float* lnb = (m < 6) ? qb : bqb;
    const float* W = (m < 6) ? Wq : bWq;
    float gvv = slots[bid * 64 + lane];
    float s = wave_sum64(gvv);
    float s2 = wave_sum64(gvv * gvv);
    float mean = s * (1.0f / 64.0f);
    float var = s2 * (1.0f / 64.0f) - mean * mean;
    float rstd = rsqrtf(var + 1e-5f);
    sx[w * 64 + lane] = (gvv - mean) * rstd * lng[lane] + lnb[lane];
    __syncthreads();
    float qd = 0.0f;
#pragma unroll 8
    for (int c = 0; c < 64; ++c) qd += sx[w * 64 + c] * W[c * 64 + lane];
    q[bid * 64 + lane] = qd;
  }
}

// ---------------------------------------------------------------------------
// proj_ln + fused attend-0: 512 threads (8 waves), 128-row tile, 64 KB LDS.
// Phase 1: LN(x) -> bf16 LDS tile (swizzled). Phase 2: MFMA -> [k|v]; store
// k/v. Phase 3: attend-0 on register-resident [k|v]; block partial written
// NON-atomically to pacc/pw (chunk = blockIdx & 127); update reduces chunks.
// ---------------------------------------------------------------------------
__global__ __launch_bounds__(512) void proj_ln_kernel(
    const float* __restrict__ inp, const float* __restrict__ lng,
    const float* __restrict__ lnb, const bf16_t* __restrict__ Wb,
    bf16_t* __restrict__ kbuf, bf16_t* __restrict__ vbuf,
    const float* __restrict__ q, float* __restrict__ pacc,
    float* __restrict__ pw) {
  __shared__ bf16_t xs[128 * 256];  // 64 KB
  __shared__ float qs[448];
  __shared__ float s_acc[448];
  __shared__ float s_w[7];
  const int tid = threadIdx.x, w = tid >> 6, lane = tid & 63;
  const int q4 = lane >> 4, lp = lane & 15;
  const long row0 = (long)blockIdx.x * 128;
  const int b = blockIdx.x >> 7;   // 128 chunks per b
  const int cb = blockIdx.x & 127;

  for (int idx = tid; idx < 448; idx += 512) {
    qs[idx] = q[b * 448 + idx];
    s_acc[idx] = 0.0f;
  }
  if (tid < 7) s_w[tid] = 0.0f;

  float4 gv[4], bv[4];
#pragma unroll
  for (int j = 0; j < 4; ++j) {
    gv[j] = *(const float4*)(lng + lp * 16 + j * 4);
    bv[j] = *(const float4*)(lnb + lp * 16 + j * 4);
  }

  // Phase 1
#pragma unroll
  for (int i = 0; i < 4; ++i) {
    int r = w * 16 + i * 4 + q4;
    const float* rp = inp + (row0 + r) * C_ + lp * 16;
    float4 x0 = *(const float4*)(rp);
    float4 x1 = *(const float4*)(rp + 4);
    float4 x2 = *(const float4*)(rp + 8);
    float4 x3 = *(const float4*)(rp + 12);
    float s = (x0.x + x0.y + x0.z + x0.w) + (x1.x + x1.y + x1.z + x1.w) +
              (x2.x + x2.y + x2.z + x2.w) + (x3.x + x3.y + x3.z + x3.w);
    float s2 = (x0.x * x0.x + x0.y * x0.y + x0.z * x0.z + x0.w * x0.w) +
               (x1.x * x1.x + x1.y * x1.y + x1.z * x1.z + x1.w * x1.w) +
               (x2.x * x2.x + x2.y * x2.y + x2.z * x2.z + x2.w * x2.w) +
               (x3.x * x3.x + x3.y * x3.y + x3.z * x3.z + x3.w * x3.w);
#pragma unroll
    for (int o = 1; o < 16; o <<= 1) {
      s += __shfl_xor(s, o);
      s2 += __shfl_xor(s2, o);
    }
    float mean = s * (1.0f / 256.0f);
    float var = s2 * (1.0f / 256.0f) - mean * mean;
    float rstd = rsqrtf(var + 1e-5f);
    bf16x8 y0, y1;
    y0[0] = (bf16_t)((x0.x - mean) * rstd * gv[0].x + bv[0].x);
    y0[1] = (bf16_t)((x0.y - mean) * rstd * gv[0].y + bv[0].y);
    y0[2] = (bf16_t)((x0.z - mean) * rstd * gv[0].z + bv[0].z);
    y0[3] = (bf16_t)((x0.w - mean) * rstd * gv[0].w + bv[0].w);
    y0[4] = (bf16_t)((x1.x - mean) * rstd * gv[1].x + bv[1].x);
    y0[5] = (bf16_t)((x1.y - mean) * rstd * gv[1].y + bv[1].y);
    y0[6] = (bf16_t)((x1.z - mean) * rstd * gv[1].z + bv[1].z);
    y0[7] = (bf16_t)((x1.w - mean) * rstd * gv[1].w + bv[1].w);
    y1[0] = (bf16_t)((x2.x - mean) * rstd * gv[2].x + bv[2].x);
    y1[1] = (bf16_t)((x2.y - mean) * rstd * gv[2].y + bv[2].y);
    y1[2] = (bf16_t)((x2.z - mean) * rstd * gv[2].z + bv[2].z);
    y1[3] = (bf16_t)((x2.w - mean) * rstd * gv[2].w + bv[2].w);
    y1[4] = (bf16_t)((x3.x - mean) * rstd * gv[3].x + bv[3].x);
    y1[5] = (bf16_t)((x3.y - mean) * rstd * gv[3].y + bv[3].y);
    y1[6] = (bf16_t)((x3.z - mean) * rstd * gv[3].z + bv[3].z);
    y1[7] = (bf16_t)((x3.w - mean) * rstd * gv[3].w + bv[3].w);
    int base = r * 32, swz = r & 31;
    *(bf16x8*)(xs + (size_t)(base + ((2 * lp) ^ swz)) * 8) = y0;
    *(bf16x8*)(xs + (size_t)(base + ((2 * lp + 1) ^ swz)) * 8) = y1;
  }
  __syncthreads();

  // Phase 2
  f32x4 acc[8];
  const f32x4 zf = {0.0f, 0.0f, 0.0f, 0.0f};
#pragma unroll
  for (int t = 0; t < 8; ++t) acc[t] = zf;

  const int r0 = w * 16 + lp;
  const int rsw = r0 & 31;
  for (int kb = 0; kb < 8; ++kb) {
    bf16x8 a = *(const bf16x8*)(xs + (size_t)(r0 * 32 + ((kb * 4 + q4) ^ rsw)) * 8);
#pragma unroll
    for (int t = 0; t < 8; ++t) {
      bf16x8 bfr = *(const bf16x8*)(Wb + (size_t)((kb * 8 + t) * 64 + lane) * 8);
      acc[t] = __builtin_amdgcn_mfma_f32_16x16x32_bf16(a, bfr, acc[t], 0, 0, 0);
    }
  }

  // Store k/v. D mapping: col = (t&3)*16 + lp, row = w*16 + q4*4 + reg.
#pragma unroll
  for (int t = 0; t < 8; ++t) {
    bf16_t* dst = (t < 4) ? kbuf : vbuf;
    int c = (t & 3) * 16 + lp;
#pragma unroll
    for (int reg = 0; reg < 4; ++reg) {
      long gr = row0 + w * 16 + q4 * 4 + reg;
      dst[gr * 64 + c] = (bf16_t)acc[t][reg];
    }
  }

  // Phase 3: fused attend-0 on register-resident [k|v].
  float av[7][4];
  float wa[7];
#pragma unroll
  for (int m = 0; m < 7; ++m) {
    wa[m] = 0.0f;
#pragma unroll
    for (int t = 0; t < 4; ++t) av[m][t] = 0.0f;
  }

#pragma unroll
  for (int reg = 0; reg < 4; ++reg) {
    float p[7];
#pragma unroll
    for (int m = 0; m < 7; ++m) p[m] = 0.0f;
#pragma unroll
    for (int t = 0; t < 4; ++t) {
      float at = acc[t][reg];
#pragma unroll
      for (int m = 0; m < 7; ++m) p[m] += at * qs[m * 64 + t * 16 + lp];
    }
#pragma unroll
    for (int m = 0; m < 7; ++m) {
      p[m] += __shfl_xor(p[m], 1);
      p[m] += __shfl_xor(p[m], 2);
      p[m] += __shfl_xor(p[m], 4);
      p[m] += __shfl_xor(p[m], 8);
    }
    float mx = -1e30f;
#pragma unroll
    for (int m = 0; m < 7; ++m) {
      p[m] *= 0.125f;  // SCALE = 64^-0.5
      mx = fmaxf(mx, p[m]);
    }
    float s = 0.0f;
#pragma unroll
    for (int m = 0; m < 7; ++m) {
      p[m] = __expf(p[m] - mx);
      s += p[m];
    }
    float inv = 1.0f / s;
#pragma unroll
    for (int m = 0; m < 7; ++m) {
      float a = p[m] * inv + 1e-6f;
      wa[m] += a;
#pragma unroll
      for (int t = 0; t < 4; ++t) av[m][t] += a * acc[4 + t][reg];
    }
  }

#pragma unroll
  for (int m = 0; m < 7; ++m) {
#pragma unroll
    for (int t = 0; t < 4; ++t) {
      av[m][t] += __shfl_xor(av[m][t], 16);
      av[m][t] += __shfl_xor(av[m][t], 32);
    }
    wa[m] += __shfl_xor(wa[m], 16);
    wa[m] += __shfl_xor(wa[m], 32);
  }
  if (q4 == 0) {
#pragma unroll
    for (int m = 0; m < 7; ++m)
#pragma unroll
      for (int t = 0; t < 4; ++t)
        atomicAdd(&s_acc[m * 64 + t * 16 + lp], av[m][t]);
  }
  if (lane == 0) {
#pragma unroll
    for (int m = 0; m < 7; ++m) atomicAdd(&s_w[m], wa[m]);
  }
  __syncthreads();
  float* pa = pacc + (size_t)(b * MAXCH + cb) * 448;
  for (int idx = tid; idx < 448; idx += 512) pa[idx] = s_acc[idx];
  if (tid < 7) pw[(b * MAXCH + cb) * 7 + tid] = s_w[tid];
}

// ---------------------------------------------------------------------------
// attend: per row: 7 logits -> softmax + EPS -> accumulate attn*v, attn.
// Block partial written non-atomically (chunk = blockIdx & 31).
// grid 1024 x 256 (one b per 32 blocks, 512 rows each). Iterations 1,2.
// ---------------------------------------------------------------------------
__global__ __launch_bounds__(256) void attend_kernel(
    const bf16_t* __restrict__ kbuf, const bf16_t* __restrict__ vbuf,
    const float* __restrict__ q, float* __restrict__ pacc,
    float* __restrict__ pw) {
  __shared__ float qs[448];
  __shared__ float s_acc[448];
  __shared__ float s_w[7];
  int tid = threadIdx.x, w = tid >> 6, lane = tid & 63;
  int g4 = lane >> 4, lp = lane & 15;
  long chunk0 = (long)blockIdx.x * 512;
  int b = blockIdx.x >> 5;
  int cb = blockIdx.x & 31;

  for (int idx = tid; idx < 448; idx += 256) {
    qs[idx] = q[b * 448 + idx];
    s_acc[idx] = 0.0f;
  }
  if (tid < 7) s_w[tid] = 0.0f;
  __syncthreads();

  float4 qv[7];
  const float4* qs4 = (const float4*)qs;
#pragma unroll
  for (int m = 0; m < 7; ++m) qv[m] = qs4[m * 16 + lp];

  float av[7][4];
  float wa[7];
#pragma unroll
  for (int m = 0; m < 7; ++m) {
    wa[m] = 0.0f;
#pragma unroll
    for (int j = 0; j < 4; ++j) av[m][j] = 0.0f;
  }

  for (int it = 0; it < 32; ++it) {
    long row = chunk0 + it * 16 + w * 4 + g4;
    bf16x4 kv = *(const bf16x4*)(kbuf + row * 64 + lp * 4);
    bf16x4 vv = *(const bf16x4*)(vbuf + row * 64 + lp * 4);
    float k0 = kv[0], k1 = kv[1], k2 = kv[2], k3 = kv[3];
    float lg[7];
#pragma unroll
    for (int m = 0; m < 7; ++m)
      lg[m] = k0 * qv[m].x + k1 * qv[m].y + k2 * qv[m].z + k3 * qv[m].w;
#pragma unroll
    for (int m = 0; m < 7; ++m) {
      lg[m] += __shfl_xor(lg[m], 1);
      lg[m] += __shfl_xor(lg[m], 2);
      lg[m] += __shfl_xor(lg[m], 4);
      lg[m] += __shfl_xor(lg[m], 8);
    }
    float mx = -1e30f;
#pragma unroll
    for (int m = 0; m < 7; ++m) {
      lg[m] *= 0.125f;
      mx = fmaxf(mx, lg[m]);
    }
    float e[7], s = 0.0f;
#pragma unroll
    for (int m = 0; m < 7; ++m) {
      e[m] = __expf(lg[m] - mx);
      s += e[m];
    }
    float inv = 1.0f / s;
    float v0 = vv[0], v1 = vv[1], v2 = vv[2], v3 = vv[3];
#pragma unroll
    for (int m = 0; m < 7; ++m) {
      float a = e[m] * inv + 1e-6f;
      wa[m] += a;
      av[m][0] += a * v0;
      av[m][1] += a * v1;
      av[m][2] += a * v2;
      av[m][3] += a * v3;
    }
  }

#pragma unroll
  for (int m = 0; m < 7; ++m) {
#pragma unroll
    for (int j = 0; j < 4; ++j) {
      av[m][j] += __shfl_xor(av[m][j], 16);
      av[m][j] += __shfl_xor(av[m][j], 32);
    }
    wa[m] += __shfl_xor(wa[m], 16);
    wa[m] += __shfl_xor(wa[m], 32);
  }
  if (g4 == 0) {
#pragma unroll
    for (int m = 0; m < 7; ++m)
#pragma unroll
      for (int j = 0; j < 4; ++j) atomicAdd(&s_acc[m * 64 + lp * 4 + j], av[m][j]);
  }
  if (lane == 0) {
#pragma unroll
    for (int m = 0; m < 7; ++m) atomicAdd(&s_w[m], wa[m]);
  }
  __syncthreads();
  float* pa = pacc + (size_t)(b * MAXCH + cb) * 448;
  for (int idx = tid; idx < 448; idx += 256) pa[idx] = s_acc[idx];
  if (tid < 7) pw[(b * MAXCH + cb) * 7 + tid] = s_w[tid];
}

// ---------------------------------------------------------------------------
// update: reduce nch chunk-partials -> fu -> GRU -> +MLP residual -> gout;
// if write_q, also q = LN(gout) @ Wq/bWq. grid 224 x 192.
// ---------------------------------------------------------------------------
__global__ __launch_bounds__(192) void update_kernel(
    const float* __restrict__ pacc, const float* __restrict__ pw, int nch,
    const float* __restrict__ g, const float* __restrict__ WihT,
    const float* __restrict__ WhhT, const float* __restrict__ bih,
    const float* __restrict__ bhh, const float* __restrict__ mlg,
    const float* __restrict__ mlb, const float* __restrict__ mW1,
    const float* __restrict__ mb1, const float* __restrict__ mW2,
    const float* __restrict__ mb2, const float* __restrict__ bmlg,
    const float* __restrict__ bmlb, const float* __restrict__ bW1,
    const float* __restrict__ bb1, const float* __restrict__ bW2,
    const float* __restrict__ bb2, float* __restrict__ gout,
    const float* __restrict__ qg, const float* __restrict__ qb,
    const float* __restrict__ Wq, const float* __restrict__ bqg,
    const float* __restrict__ bqb, const float* __restrict__ bWq,
    float* __restrict__ qout, int write_q) {
  __shared__ float fu[64], hp[64], gi[192], gh[192], h2[64], xb[64], a1[128], go[64];
  int tid = threadIdx.x, bid = blockIdx.x, m = bid % 7, b = bid / 7;

  const float *lg_, *lb_, *W1_, *b1_, *W2_, *b2_;
  if (m < 6) { lg_ = mlg; lb_ = mlb; W1_ = mW1; b1_ = mb1; W2_ = mW2; b2_ = mb2; }
  else       { lg_ = bmlg; lb_ = bmlb; W1_ = bW1; b1_ = bb1; W2_ = bW2; b2_ = bb2; }

  if (tid < 64) {
    // reduce chunk partials (coalesced: 64 lanes x 4B per chunk)
    const float* pa = pacc + (size_t)b * MAXCH * 448 + m * 64 + tid;
    float s = 0.0f;
#pragma unroll 8
    for (int c = 0; c < nch; ++c) s += pa[(size_t)c * 448];
    const float* pwp = pw + (size_t)b * MAXCH * 7 + m;
    float wp = 0.0f;
    if (tid < nch) wp = pwp[tid * 7];
    if (tid + 64 < nch) wp += pwp[(tid + 64) * 7];
    float wv = wave_sum64(wp);
    fu[tid] = s / wv;
    hp[tid] = g[bid * 64 + tid];
  }
  __syncthreads();

  {
    int j = tid;
    float a = bih[j], bsum = bhh[j];
    for (int c = 0; c < 64; ++c) {
      a += fu[c] * WihT[c * 192 + j];
      bsum += hp[c] * WhhT[c * 192 + j];
    }
    gi[j] = a;
    gh[j] = bsum;
  }
  __syncthreads();

  if (tid < 64) {
    int d = tid;
    float r = sigmoidf_(gi[d] + gh[d]);
    float z = sigmoidf_(gi[64 + d] + gh[64 + d]);
    float n = tanhf_(gi[128 + d] + r * gh[128 + d]);
    float h = (1.0f - z) * n + z * hp[d];
    h2[d] = h;
    float s = wave_sum64(h);
    float s2 = wave_sum64(h * h);
    float mean = s * (1.0f / 64.0f);
    float var = s2 * (1.0f / 64.0f) - mean * mean;
    xb[d] = (h - mean) * rsqrtf(var + 1e-5f) * lg_[d] + lb_[d];
  }
  __syncthreads();

  if (tid < 128) {
    int hh = tid;
    float a = b1_[hh];
    for (int c = 0; c < 64; ++c) a += xb[c] * W1_[c * 128 + hh];
    a1[hh] = fmaxf(a, 0.0f);
  }
  __syncthreads();

  if (tid < 64) {
    int d = tid;
    float o = b2_[d];
    for (int hh = 0; hh < 128; ++hh) o += a1[hh] * W2_[hh * 64 + d];
    float res = h2[d] + o;
    gout[bid * 64 + d] = res;
    go[d] = res;
  }
  __syncthreads();

  if (write_q) {
    if (tid < 64) {
      const float* qlng = (m < 6) ? qg : bqg;
      const float* qlnb = (m < 6) ? qb : bqb;
      const float* W = (m < 6) ? Wq : bWq;
      float gvv = go[tid];
      float s = wave_sum64(gvv);
      float s2 = wave_sum64(gvv * gvv);
      float mean = s * (1.0f / 64.0f);
      float var = s2 * (1.0f / 64.0f) - mean * mean;
      xb[tid] = (gvv - mean) * rsqrtf(var + 1e-5f) * qlng[tid] + qlnb[tid];
      __syncwarp();
      float qd = 0.0f;
#pragma unroll 8
      for (int c = 0; c < 64; ++c) qd += xb[c] * W[c * 64 + tid];
      qout[bid * 64 + tid] = qd;
    }
  }
}

// ---------------------------------------------------------------------------
extern "C" void kernel_launch(void* const* d_in, const int* in_sizes, int n_in,
                              void* d_out, int out_size, void* d_ws, size_t ws_size,
                              hipStream_t stream) {
  const float* inputs   = (const float*)d_in[0];
  const float* slots_mu = (const float*)d_in[1];
  const float* ln_in_g  = (const float*)d_in[2];
  const float* ln_in_b  = (const float*)d_in[3];
  const float* Wk       = (const float*)d_in[4];
  const float* Wv       = (const float*)d_in[5];
  const float* q_ln_g   = (const float*)d_in[6];
  const float* q_ln_b   = (const float*)d_in[7];
  const float* Wq       = (const float*)d_in[8];
  const float* bq_ln_g  = (const float*)d_in[9];
  const float* bq_ln_b  = (const float*)d_in[10];
  const float* bWq      = (const float*)d_in[11];
  const float* gru_Wih  = (const float*)d_in[12];
  const float* gru_Whh  = (const float*)d_in[13];
  const float* gru_bih  = (const float*)d_in[14];
  const float* gru_bhh  = (const float*)d_in[15];
  const float* mlp_ln_g = (const float*)d_in[16];
  const float* mlp_ln_b = (const float*)d_in[17];
  const float* mlp_W1   = (const float*)d_in[18];
  const float* mlp_b1   = (const float*)d_in[19];
  const float* mlp_W2   = (const float*)d_in[20];
  const float* mlp_b2   = (const float*)d_in[21];
  const float* bmlp_ln_g = (const float*)d_in[22];
  const float* bmlp_ln_b = (const float*)d_in[23];
  const float* bmlp_W1  = (const float*)d_in[24];
  const float* bmlp_b1  = (const float*)d_in[25];
  const float* bmlp_W2  = (const float*)d_in[26];
  const float* bmlp_b2  = (const float*)d_in[27];
  float* out = (float*)d_out;

  char* ws = (char*)d_ws;
  const size_t KV_BYTES = (size_t)ROWS_TOTAL * 64 * 2;  // 64 MB each
  size_t off = 0;
  bf16_t* kbuf = (bf16_t*)(ws + off); off += KV_BYTES;
  bf16_t* vbuf = (bf16_t*)(ws + off); off += KV_BYTES;
  bf16_t* Wb   = (bf16_t*)(ws + off); off += 65536;
  float* WihT  = (float*)(ws + off);  off += 49152;
  float* WhhT  = (float*)(ws + off);  off += 49152;
  float* gbuf  = (float*)(ws + off);  off += 57344;
  float* qbuf  = (float*)(ws + off);  off += 57344;
  float* pacc  = (float*)(ws + off);  off += (size_t)B_ * MAXCH * 448 * 4;  // 7.34 MB
  float* pw    = (float*)(ws + off);  off += (size_t)B_ * MAXCH * 7 * 4;

  prep_kernel<<<336, 256, 0, stream>>>(Wk, Wv, gru_Wih, gru_Whh, slots_mu,
                                       q_ln_g, q_ln_b, Wq, bq_ln_g, bq_ln_b,
                                       bWq, Wb, WihT, WhhT, gbuf, qbuf);
  proj_ln_kernel<<<ROWS_TOTAL / 128, 512, 0, stream>>>(
      inputs, ln_in_g, ln_in_b, Wb, kbuf, vbuf, qbuf, pacc, pw);
  for (int it = 0; it < 3; ++it) {
    if (it > 0)
      attend_kernel<<<ROWS_TOTAL / 512, 256, 0, stream>>>(kbuf, vbuf, qbuf,
                                                          pacc, pw);
    update_kernel<<<224, 192, 0, stream>>>(
        pacc, pw, (it == 0) ? 128 : 32, gbuf, WihT, WhhT, gru_bih, gru_bhh,
        mlp_ln_g, mlp_ln_b, mlp_W1, mlp_b1, mlp_W2, mlp_b2, bmlp_ln_g,
        bmlp_ln_b, bmlp_W1, bmlp_b1, bmlp_W2, bmlp_b2, (it == 2) ? out : gbuf,
        q_ln_g, q_ln_b, Wq, bq_ln_g, bq_ln_b, bWq, qbuf, (it < 2) ? 1 : 0);
  }
}

// Round 3
// 1033.228 us; speedup vs baseline: 1.0356x; 1.0356x over previous
//
#include <hip/hip_runtime.h>
#include <hip/hip_bf16.h>

typedef __bf16 bf16_t;
typedef __bf16 bf16x4 __attribute__((ext_vector_type(4)));
typedef __bf16 bf16x8 __attribute__((ext_vector_type(8)));
typedef float f32x4 __attribute__((ext_vector_type(4)));

#define B_ 32
#define N_ 16384
#define C_ 256
#define D_ 64
#define ROWS_TOTAL (B_ * N_)  // 524288
#define NCH 32                // partial chunks per b (attend grid: 32 blocks/b)

__device__ inline float wave_sum64(float v) {
#pragma unroll
  for (int o = 1; o < 64; o <<= 1) v += __shfl_xor(v, o);
  return v;
}

__device__ inline float sigmoidf_(float x) { return 1.0f / (1.0f + __expf(-x)); }
__device__ inline float tanhf_(float x) { return 1.0f - 2.0f / (__expf(2.0f * x) + 1.0f); }

// ---------------------------------------------------------------------------
// prep (+ fused qk): blocks 0..279: Wb = [Wk|Wv] in MFMA B-frag layout,
// transpose GRU weights, g = slots. Blocks 280..335: iteration-0
// q = LN(slots[b,m]) @ Wq/bWq. grid 336 x 256.
// ---------------------------------------------------------------------------
__global__ __launch_bounds__(256) void prep_kernel(
    const float* __restrict__ Wk, const float* __restrict__ Wv,
    const float* __restrict__ Wih, const float* __restrict__ Whh,
    const float* __restrict__ slots, const float* __restrict__ qg,
    const float* __restrict__ qb, const float* __restrict__ Wq,
    const float* __restrict__ bqg, const float* __restrict__ bqb,
    const float* __restrict__ bWq, bf16_t* __restrict__ Wb,
    float* __restrict__ WihT, float* __restrict__ WhhT, float* __restrict__ g,
    float* __restrict__ q) {
  __shared__ float sx[256];
  if (blockIdx.x < 280) {
    int i = blockIdx.x * 256 + threadIdx.x;
    if (i < 32768) {
      int j = i & 7, l = (i >> 3) & 63, t = (i >> 9) & 7, kb = i >> 12;
      int k = kb * 32 + (l >> 4) * 8 + j;
      int n = t * 16 + (l & 15);
      float v = (n < 64) ? Wk[k * 64 + n] : Wv[k * 64 + (n - 64)];
      Wb[i] = (bf16_t)v;
    } else if (i < 45056) {
      int idx = i - 32768;
      int c = idx / 192, j = idx % 192;
      WihT[idx] = Wih[j * 64 + c];
    } else if (i < 57344) {
      int idx = i - 45056;
      int c = idx / 192, j = idx % 192;
      WhhT[idx] = Whh[j * 64 + c];
    } else if (i < 71680) {
      int idx = i - 57344;
      g[idx] = slots[idx];
    }
  } else {
    int w = threadIdx.x >> 6, lane = threadIdx.x & 63;
    int bid = (blockIdx.x - 280) * 4 + w;  // 0..223 = b*7+m
    int m = bid % 7;
    const float* lng = (m < 6) ? qg : bqg;
    const float* lnb = (m < 6) ? qb : bqb;
    const float* W = (m < 6) ? Wq : bWq;
    float gvv = slots[bid * 64 + lane];
    float s = wave_sum64(gvv);
    float s2 = wave_sum64(gvv * gvv);
    float mean = s * (1.0f / 64.0f);
    float var = s2 * (1.0f / 64.0f) - mean * mean;
    float rstd = rsqrtf(var + 1e-5f);
    sx[w * 64 + lane] = (gvv - mean) * rstd * lng[lane] + lnb[lane];
    __syncthreads();
    float qd = 0.0f;
#pragma unroll 8
    for (int c = 0; c < 64; ++c) qd += sx[w * 64 + c] * W[c * 64 + lane];
    q[bid * 64 + lane] = qd;
  }
}

// ---------------------------------------------------------------------------
// proj_ln v2 (baseline): 512 threads (8 waves), 128-row tile, 64 KB LDS ->
// 2 blocks/CU. Phase 1: LN -> bf16 LDS tile (swizzled). Phase 2: MFMA ->
// [k|v], store to global. NO attend fusion (keeps VGPR <= 128 for occupancy).
// ---------------------------------------------------------------------------
__global__ __launch_bounds__(512) void proj_ln_kernel(
    const float* __restrict__ inp, const float* __restrict__ lng,
    const float* __restrict__ lnb, const bf16_t* __restrict__ Wb,
    bf16_t* __restrict__ kbuf, bf16_t* __restrict__ vbuf) {
  __shared__ bf16_t xs[128 * 256];  // 64 KB
  const int tid = threadIdx.x, w = tid >> 6, lane = tid & 63;
  const int q4 = lane >> 4, lp = lane & 15;
  const long row0 = (long)blockIdx.x * 128;

  float4 gv[4], bv[4];
#pragma unroll
  for (int j = 0; j < 4; ++j) {
    gv[j] = *(const float4*)(lng + lp * 16 + j * 4);
    bv[j] = *(const float4*)(lnb + lp * 16 + j * 4);
  }

  // Phase 1: wave w -> rows w*16 .. w*16+15
#pragma unroll
  for (int i = 0; i < 4; ++i) {
    int r = w * 16 + i * 4 + q4;
    const float* rp = inp + (row0 + r) * C_ + lp * 16;
    float4 x0 = *(const float4*)(rp);
    float4 x1 = *(const float4*)(rp + 4);
    float4 x2 = *(const float4*)(rp + 8);
    float4 x3 = *(const float4*)(rp + 12);
    float s = (x0.x + x0.y + x0.z + x0.w) + (x1.x + x1.y + x1.z + x1.w) +
              (x2.x + x2.y + x2.z + x2.w) + (x3.x + x3.y + x3.z + x3.w);
    float s2 = (x0.x * x0.x + x0.y * x0.y + x0.z * x0.z + x0.w * x0.w) +
               (x1.x * x1.x + x1.y * x1.y + x1.z * x1.z + x1.w * x1.w) +
               (x2.x * x2.x + x2.y * x2.y + x2.z * x2.z + x2.w * x2.w) +
               (x3.x * x3.x + x3.y * x3.y + x3.z * x3.z + x3.w * x3.w);
#pragma unroll
    for (int o = 1; o < 16; o <<= 1) {
      s += __shfl_xor(s, o);
      s2 += __shfl_xor(s2, o);
    }
    float mean = s * (1.0f / 256.0f);
    float var = s2 * (1.0f / 256.0f) - mean * mean;
    float rstd = rsqrtf(var + 1e-5f);
    bf16x8 y0, y1;
    y0[0] = (bf16_t)((x0.x - mean) * rstd * gv[0].x + bv[0].x);
    y0[1] = (bf16_t)((x0.y - mean) * rstd * gv[0].y + bv[0].y);
    y0[2] = (bf16_t)((x0.z - mean) * rstd * gv[0].z + bv[0].z);
    y0[3] = (bf16_t)((x0.w - mean) * rstd * gv[0].w + bv[0].w);
    y0[4] = (bf16_t)((x1.x - mean) * rstd * gv[1].x + bv[1].x);
    y0[5] = (bf16_t)((x1.y - mean) * rstd * gv[1].y + bv[1].y);
    y0[6] = (bf16_t)((x1.z - mean) * rstd * gv[1].z + bv[1].z);
    y0[7] = (bf16_t)((x1.w - mean) * rstd * gv[1].w + bv[1].w);
    y1[0] = (bf16_t)((x2.x - mean) * rstd * gv[2].x + bv[2].x);
    y1[1] = (bf16_t)((x2.y - mean) * rstd * gv[2].y + bv[2].y);
    y1[2] = (bf16_t)((x2.z - mean) * rstd * gv[2].z + bv[2].z);
    y1[3] = (bf16_t)((x2.w - mean) * rstd * gv[2].w + bv[2].w);
    y1[4] = (bf16_t)((x3.x - mean) * rstd * gv[3].x + bv[3].x);
    y1[5] = (bf16_t)((x3.y - mean) * rstd * gv[3].y + bv[3].y);
    y1[6] = (bf16_t)((x3.z - mean) * rstd * gv[3].z + bv[3].z);
    y1[7] = (bf16_t)((x3.w - mean) * rstd * gv[3].w + bv[3].w);
    int base = r * 32, swz = r & 31;
    *(bf16x8*)(xs + (size_t)(base + ((2 * lp) ^ swz)) * 8) = y0;
    *(bf16x8*)(xs + (size_t)(base + ((2 * lp + 1) ^ swz)) * 8) = y1;
  }
  __syncthreads();

  // Phase 2: wave w -> 16-row m-tile rows w*16..+15
  f32x4 acc[8];
  const f32x4 zf = {0.0f, 0.0f, 0.0f, 0.0f};
#pragma unroll
  for (int t = 0; t < 8; ++t) acc[t] = zf;

  const int r0 = w * 16 + lp;
  const int rsw = r0 & 31;
  for (int kb = 0; kb < 8; ++kb) {
    bf16x8 a = *(const bf16x8*)(xs + (size_t)(r0 * 32 + ((kb * 4 + q4) ^ rsw)) * 8);
#pragma unroll
    for (int t = 0; t < 8; ++t) {
      bf16x8 bfr = *(const bf16x8*)(Wb + (size_t)((kb * 8 + t) * 64 + lane) * 8);
      acc[t] = __builtin_amdgcn_mfma_f32_16x16x32_bf16(a, bfr, acc[t], 0, 0, 0);
    }
  }

  // Epilogue: D mapping col = lane&15, row = (lane>>4)*4 + reg
#pragma unroll
  for (int t = 0; t < 8; ++t) {
    bf16_t* dst = (t < 4) ? kbuf : vbuf;
    int c = (t & 3) * 16 + lp;
#pragma unroll
    for (int reg = 0; reg < 4; ++reg) {
      long gr = row0 + w * 16 + q4 * 4 + reg;
      dst[gr * 64 + c] = (bf16_t)acc[t][reg];
    }
  }
}

// ---------------------------------------------------------------------------
// attend: per row: 7 logits -> softmax + EPS -> accumulate attn*v, attn.
// Block partial written NON-atomically to pacc/pw (chunk = blockIdx & 31);
// update reduces the 32 chunk partials. grid 1024 x 256 (32 blocks/b).
// ---------------------------------------------------------------------------
__global__ __launch_bounds__(256) void attend_kernel(
    const bf16_t* __restrict__ kbuf, const bf16_t* __restrict__ vbuf,
    const float* __restrict__ q, float* __restrict__ pacc,
    float* __restrict__ pw) {
  __shared__ float qs[448];
  __shared__ float s_acc[448];
  __shared__ float s_w[7];
  int tid = threadIdx.x, w = tid >> 6, lane = tid & 63;
  int g4 = lane >> 4, lp = lane & 15;
  long chunk0 = (long)blockIdx.x * 512;
  int b = blockIdx.x >> 5;
  int cb = blockIdx.x & 31;

  for (int idx = tid; idx < 448; idx += 256) {
    qs[idx] = q[b * 448 + idx];
    s_acc[idx] = 0.0f;
  }
  if (tid < 7) s_w[tid] = 0.0f;
  __syncthreads();

  // hoist q fragments out of the K-loop
  float4 qv[7];
  const float4* qs4 = (const float4*)qs;
#pragma unroll
  for (int m = 0; m < 7; ++m) qv[m] = qs4[m * 16 + lp];

  float av[7][4];
  float wa[7];
#pragma unroll
  for (int m = 0; m < 7; ++m) {
    wa[m] = 0.0f;
#pragma unroll
    for (int j = 0; j < 4; ++j) av[m][j] = 0.0f;
  }

  for (int it = 0; it < 32; ++it) {
    long row = chunk0 + it * 16 + w * 4 + g4;
    bf16x4 kv = *(const bf16x4*)(kbuf + row * 64 + lp * 4);
    bf16x4 vv = *(const bf16x4*)(vbuf + row * 64 + lp * 4);
    float k0 = kv[0], k1 = kv[1], k2 = kv[2], k3 = kv[3];
    float lg[7];
#pragma unroll
    for (int m = 0; m < 7; ++m)
      lg[m] = k0 * qv[m].x + k1 * qv[m].y + k2 * qv[m].z + k3 * qv[m].w;
#pragma unroll
    for (int m = 0; m < 7; ++m) {
      lg[m] += __shfl_xor(lg[m], 1);
      lg[m] += __shfl_xor(lg[m], 2);
      lg[m] += __shfl_xor(lg[m], 4);
      lg[m] += __shfl_xor(lg[m], 8);
    }
    float mx = -1e30f;
#pragma unroll
    for (int m = 0; m < 7; ++m) {
      lg[m] *= 0.125f;
      mx = fmaxf(mx, lg[m]);
    }
    float e[7], s = 0.0f;
#pragma unroll
    for (int m = 0; m < 7; ++m) {
      e[m] = __expf(lg[m] - mx);
      s += e[m];
    }
    float inv = 1.0f / s;
    float v0 = vv[0], v1 = vv[1], v2 = vv[2], v3 = vv[3];
#pragma unroll
    for (int m = 0; m < 7; ++m) {
      float a = e[m] * inv + 1e-6f;
      wa[m] += a;
      av[m][0] += a * v0;
      av[m][1] += a * v1;
      av[m][2] += a * v2;
      av[m][3] += a * v3;
    }
  }

#pragma unroll
  for (int m = 0; m < 7; ++m) {
#pragma unroll
    for (int j = 0; j < 4; ++j) {
      av[m][j] += __shfl_xor(av[m][j], 16);
      av[m][j] += __shfl_xor(av[m][j], 32);
    }
    wa[m] += __shfl_xor(wa[m], 16);
    wa[m] += __shfl_xor(wa[m], 32);
  }
  if (g4 == 0) {
#pragma unroll
    for (int m = 0; m < 7; ++m)
#pragma unroll
      for (int j = 0; j < 4; ++j) atomicAdd(&s_acc[m * 64 + lp * 4 + j], av[m][j]);
  }
  if (lane == 0) {
#pragma unroll
    for (int m = 0; m < 7; ++m) atomicAdd(&s_w[m], wa[m]);
  }
  __syncthreads();
  float* pa = pacc + (size_t)(b * NCH + cb) * 448;
  for (int idx = tid; idx < 448; idx += 256) pa[idx] = s_acc[idx];
  if (tid < 7) pw[(b * NCH + cb) * 7 + tid] = s_w[tid];
}

// ---------------------------------------------------------------------------
// update: reduce 32 chunk-partials -> fu -> GRU -> +MLP residual -> gout;
// if write_q, also q = LN(gout) @ Wq/bWq. grid 224 x 192.
// ---------------------------------------------------------------------------
__global__ __launch_bounds__(192) void update_kernel(
    const float* __restrict__ pacc, const float* __restrict__ pw,
    const float* __restrict__ g, const float* __restrict__ WihT,
    const float* __restrict__ WhhT, const float* __restrict__ bih,
    const float* __restrict__ bhh, const float* __restrict__ mlg,
    const float* __restrict__ mlb, const float* __restrict__ mW1,
    const float* __restrict__ mb1, const float* __restrict__ mW2,
    const float* __restrict__ mb2, const float* __restrict__ bmlg,
    const float* __restrict__ bmlb, const float* __restrict__ bW1,
    const float* __restrict__ bb1, const float* __restrict__ bW2,
    const float* __restrict__ bb2, float* __restrict__ gout,
    const float* __restrict__ qg, const float* __restrict__ qb,
    const float* __restrict__ Wq, const float* __restrict__ bqg,
    const float* __restrict__ bqb, const float* __restrict__ bWq,
    float* __restrict__ qout, int write_q) {
  __shared__ float fu[64], hp[64], gi[192], gh[192], h2[64], xb[64], a1[128], go[64];
  int tid = threadIdx.x, bid = blockIdx.x, m = bid % 7, b = bid / 7;

  const float *lg_, *lb_, *W1_, *b1_, *W2_, *b2_;
  if (m < 6) { lg_ = mlg; lb_ = mlb; W1_ = mW1; b1_ = mb1; W2_ = mW2; b2_ = mb2; }
  else       { lg_ = bmlg; lb_ = bmlb; W1_ = bW1; b1_ = bb1; W2_ = bW2; b2_ = bb2; }

  if (tid < 64) {
    // reduce chunk partials (coalesced: 64 lanes x 4B per chunk)
    const float* pa = pacc + (size_t)b * NCH * 448 + m * 64 + tid;
    float s = 0.0f;
#pragma unroll 8
    for (int c = 0; c < NCH; ++c) s += pa[(size_t)c * 448];
    const float* pwp = pw + (size_t)b * NCH * 7 + m;
    float wp = (tid < NCH) ? pwp[tid * 7] : 0.0f;
    float wv = wave_sum64(wp);
    fu[tid] = s / wv;
    hp[tid] = g[bid * 64 + tid];
  }
  __syncthreads();

  {
    int j = tid;
    float a = bih[j], bsum = bhh[j];
    for (int c = 0; c < 64; ++c) {
      a += fu[c] * WihT[c * 192 + j];
      bsum += hp[c] * WhhT[c * 192 + j];
    }
    gi[j] = a;
    gh[j] = bsum;
  }
  __syncthreads();

  if (tid < 64) {
    int d = tid;
    float r = sigmoidf_(gi[d] + gh[d]);
    float z = sigmoidf_(gi[64 + d] + gh[64 + d]);
    float n = tanhf_(gi[128 + d] + r * gh[128 + d]);
    float h = (1.0f - z) * n + z * hp[d];
    h2[d] = h;
    float s = wave_sum64(h);
    float s2 = wave_sum64(h * h);
    float mean = s * (1.0f / 64.0f);
    float var = s2 * (1.0f / 64.0f) - mean * mean;
    xb[d] = (h - mean) * rsqrtf(var + 1e-5f) * lg_[d] + lb_[d];
  }
  __syncthreads();

  if (tid < 128) {
    int hh = tid;
    float a = b1_[hh];
    for (int c = 0; c < 64; ++c) a += xb[c] * W1_[c * 128 + hh];
    a1[hh] = fmaxf(a, 0.0f);
  }
  __syncthreads();

  if (tid < 64) {
    int d = tid;
    float o = b2_[d];
    for (int hh = 0; hh < 128; ++hh) o += a1[hh] * W2_[hh * 64 + d];
    float res = h2[d] + o;
    gout[bid * 64 + d] = res;
    go[d] = res;
  }
  __syncthreads();

  if (write_q) {
    if (tid < 64) {
      const float* qlng = (m < 6) ? qg : bqg;
      const float* qlnb = (m < 6) ? qb : bqb;
      const float* W = (m < 6) ? Wq : bWq;
      float gvv = go[tid];
      float s = wave_sum64(gvv);
      float s2 = wave_sum64(gvv * gvv);
      float mean = s * (1.0f / 64.0f);
      float var = s2 * (1.0f / 64.0f) - mean * mean;
      xb[tid] = (gvv - mean) * rsqrtf(var + 1e-5f) * qlng[tid] + qlnb[tid];
      __syncwarp();
      float qd = 0.0f;
#pragma unroll 8
      for (int c = 0; c < 64; ++c) qd += xb[c] * W[c * 64 + tid];
      qout[bid * 64 + tid] = qd;
    }
  }
}

// ---------------------------------------------------------------------------
extern "C" void kernel_launch(void* const* d_in, const int* in_sizes, int n_in,
                              void* d_out, int out_size, void* d_ws, size_t ws_size,
                              hipStream_t stream) {
  const float* inputs   = (const float*)d_in[0];
  const float* slots_mu = (const float*)d_in[1];
  const float* ln_in_g  = (const float*)d_in[2];
  const float* ln_in_b  = (const float*)d_in[3];
  const float* Wk       = (const float*)d_in[4];
  const float* Wv       = (const float*)d_in[5];
  const float* q_ln_g   = (const float*)d_in[6];
  const float* q_ln_b   = (const float*)d_in[7];
  const float* Wq       = (const float*)d_in[8];
  const float* bq_ln_g  = (const float*)d_in[9];
  const float* bq_ln_b  = (const float*)d_in[10];
  const float* bWq      = (const float*)d_in[11];
  const float* gru_Wih  = (const float*)d_in[12];
  const float* gru_Whh  = (const float*)d_in[13];
  const float* gru_bih  = (const float*)d_in[14];
  const float* gru_bhh  = (const float*)d_in[15];
  const float* mlp_ln_g = (const float*)d_in[16];
  const float* mlp_ln_b = (const float*)d_in[17];
  const float* mlp_W1   = (const float*)d_in[18];
  const float* mlp_b1   = (const float*)d_in[19];
  const float* mlp_W2   = (const float*)d_in[20];
  const float* mlp_b2   = (const float*)d_in[21];
  const float* bmlp_ln_g = (const float*)d_in[22];
  const float* bmlp_ln_b = (const float*)d_in[23];
  const float* bmlp_W1  = (const float*)d_in[24];
  const float* bmlp_b1  = (const float*)d_in[25];
  const float* bmlp_W2  = (const float*)d_in[26];
  const float* bmlp_b2  = (const float*)d_in[27];
  float* out = (float*)d_out;

  char* ws = (char*)d_ws;
  const size_t KV_BYTES = (size_t)ROWS_TOTAL * 64 * 2;  // 64 MB each
  size_t off = 0;
  bf16_t* kbuf = (bf16_t*)(ws + off); off += KV_BYTES;
  bf16_t* vbuf = (bf16_t*)(ws + off); off += KV_BYTES;
  bf16_t* Wb   = (bf16_t*)(ws + off); off += 65536;
  float* WihT  = (float*)(ws + off);  off += 49152;
  float* WhhT  = (float*)(ws + off);  off += 49152;
  float* gbuf  = (float*)(ws + off);  off += 57344;
  float* qbuf  = (float*)(ws + off);  off += 57344;
  float* pacc  = (float*)(ws + off);  off += (size_t)B_ * NCH * 448 * 4;  // 1.84 MB
  float* pw    = (float*)(ws + off);  off += (size_t)B_ * NCH * 7 * 4;

  prep_kernel<<<336, 256, 0, stream>>>(Wk, Wv, gru_Wih, gru_Whh, slots_mu,
                                       q_ln_g, q_ln_b, Wq, bq_ln_g, bq_ln_b,
                                       bWq, Wb, WihT, WhhT, gbuf, qbuf);
  proj_ln_kernel<<<ROWS_TOTAL / 128, 512, 0, stream>>>(inputs, ln_in_g, ln_in_b,
                                                       Wb, kbuf, vbuf);
  for (int it = 0; it < 3; ++it) {
    attend_kernel<<<ROWS_TOTAL / 512, 256, 0, stream>>>(kbuf, vbuf, qbuf, pacc,
                                                        pw);
    update_kernel<<<224, 192, 0, stream>>>(
        pacc, pw, gbuf, WihT, WhhT, gru_bih, gru_bhh, mlp_ln_g, mlp_ln_b,
        mlp_W1, mlp_b1, mlp_W2, mlp_b2, bmlp_ln_g, bmlp_ln_b, bmlp_W1, bmlp_b1,
        bmlp_W2, bmlp_b2, (it == 2) ? out : gbuf, q_ln_g, q_ln_b, Wq, bq_ln_g,
        bq_ln_b, bWq, qbuf, (it < 2) ? 1 : 0);
  }
}